// Round 4
// baseline (17282.333 us; speedup 1.0000x reference)
//
#include <hip/hip_runtime.h>
#include <hip/hip_bf16.h>
#include <stdint.h>

#define DIMS 2048
#define SEQ  4096
#define NBLK 128   // persistent blocks for the recurrence
#define RPB  16    // rows of W_hh per block (NBLK*RPB == DIMS)

typedef unsigned long long ull;

// ---------- helpers ----------
__device__ __forceinline__ unsigned pk_bf16(float a, float b) {
  unsigned ua = __float_as_uint(a);
  ua += 0x7fffu + ((ua >> 16) & 1u);
  unsigned ub = __float_as_uint(b);
  ub += 0x7fffu + ((ub >> 16) & 1u);
  return (ua >> 16) | (ub & 0xffff0000u);
}
__device__ __forceinline__ float bflo(unsigned u) { return __uint_as_float(u << 16); }
__device__ __forceinline__ float bfhi(unsigned u) { return __uint_as_float(u & 0xffff0000u); }

// ---------- Kernel A: Z = X @ W_hi^T + b  (fp32, written into d_out) ----------
__global__ __launch_bounds__(256) void gemm_z(const float* __restrict__ X,
                                              const float* __restrict__ W,
                                              const float* __restrict__ bias,
                                              float* __restrict__ Z) {
  __shared__ float xs[64][33];
  __shared__ float ws[64][33];
  const int tid = threadIdx.x;
  const int tx = tid & 15;
  const int ty = tid >> 4;
  const int s0 = blockIdx.x * 64;
  const int d0 = blockIdx.y * 64;

  float acc[4][4] = {};

  for (int k0 = 0; k0 < DIMS; k0 += 32) {
#pragma unroll
    for (int i = 0; i < 2; ++i) {
      int idx = tid + i * 256;
      int r = idx >> 3;
      int c = (idx & 7) << 2;
      float4 xv = *(const float4*)&X[(size_t)(s0 + r) * DIMS + k0 + c];
      xs[r][c] = xv.x; xs[r][c + 1] = xv.y; xs[r][c + 2] = xv.z; xs[r][c + 3] = xv.w;
      float4 wv = *(const float4*)&W[(size_t)(d0 + r) * DIMS + k0 + c];
      ws[r][c] = wv.x; ws[r][c + 1] = wv.y; ws[r][c + 2] = wv.z; ws[r][c + 3] = wv.w;
    }
    __syncthreads();
#pragma unroll
    for (int k = 0; k < 32; ++k) {
      float a_[4], b_[4];
#pragma unroll
      for (int i = 0; i < 4; ++i) a_[i] = xs[ty * 4 + i][k];
#pragma unroll
      for (int j = 0; j < 4; ++j) b_[j] = ws[tx * 4 + j][k];
#pragma unroll
      for (int i = 0; i < 4; ++i)
#pragma unroll
        for (int j = 0; j < 4; ++j) acc[i][j] += a_[i] * b_[j];
    }
    __syncthreads();
  }

  const float4 bv = *(const float4*)&bias[d0 + tx * 4];
#pragma unroll
  for (int i = 0; i < 4; ++i) {
    float4 o;
    o.x = acc[i][0] + bv.x; o.y = acc[i][1] + bv.y;
    o.z = acc[i][2] + bv.z; o.w = acc[i][3] + bv.w;
    *(float4*)&Z[(size_t)(s0 + ty * 4 + i) * DIMS + d0 + tx * 4] = o;
  }
}

// ---------- Kernel B: persistent recurrence, single-counter barrier ----------
// ctr: 8 rotating counters (each on its own 64B line), monotonic targets:
//   step t is ready when ctr[t&7] >= NBLK * ((t>>3)+1). Never reset -> replay
//   safe (memset 0 at launch). Each block: ONE atomicAdd per step (after its
//   h stores drained by the vmcnt(0) in __syncthreads), ONE polling lane.
// h double buffer: step t reads slot (t+1)&1, writes slot t&1. A block can
// only reach the add for step t+1 after consuming slot ((t+1)+1)&1, so slot
// overwrite at t+2 is safe by induction (same argument as before).
__global__ __launch_bounds__(256) void rnn_seq(const float* __restrict__ X,
                                               const float* __restrict__ Whh,
                                               const float* __restrict__ h0,
                                               float* __restrict__ ZO,   // d_out: Z in, out overwrites
                                               float* __restrict__ hb,   // ws: 2*DIMS floats
                                               int* __restrict__ ctr)    // ws: 8 counters, stride 16 ints
{
  __shared__ uint4  w16[16][RPB][16];  // [j4][row][kk]
  __shared__ float4 hs4[DIMS / 4];     // swizzled h_{t-1}

  const int tid = threadIdx.x;
  const int b   = blockIdx.x;
  const int r   = tid >> 4;            // 0..15
  const int kk  = tid & 15;            // 0..15
  const int grow = b * RPB + r;

  // ---- one-time: pack W_hh rows into LDS as bf16 pairs ----
  {
    const float* wrow = Whh + (size_t)grow * DIMS + kk * 128;
#pragma unroll 4
    for (int j4 = 0; j4 < 16; ++j4) {
      float4 f0 = *(const float4*)(wrow + j4 * 8);
      float4 f1 = *(const float4*)(wrow + j4 * 8 + 4);
      w16[j4][r][kk] = make_uint4(pk_bf16(f0.x, f0.y), pk_bf16(f0.z, f0.w),
                                  pk_bf16(f1.x, f1.y), pk_bf16(f1.z, f1.w));
    }
  }
  // ---- publish h0 slice into slot 1 ----
  if (tid < RPB) {
    __hip_atomic_store(&hb[DIMS + b * RPB + tid], h0[b * RPB + tid],
                       __ATOMIC_RELAXED, __HIP_MEMORY_SCOPE_AGENT);
  }
  // prefetch Z[0][grow], X[0][grow]
  float zpre = 0.f, xpre = 0.f;
  if (kk == 0) {
    zpre = ZO[grow];
    xpre = X[grow];
  }
  __syncthreads();   // drains h0 stores (vmcnt)
  if (tid == 0)
    __hip_atomic_fetch_add(&ctr[0], 1, __ATOMIC_RELAXED, __HIP_MEMORY_SCOPE_AGENT);

  for (int t = 0; t < SEQ; ++t) {
    // ---- wait: single lane polls single counter line ----
    if (tid == 0) {
      const int target = ((t >> 3) + 1) * NBLK;
      while (__hip_atomic_load(&ctr[(t & 7) * 16], __ATOMIC_RELAXED,
                               __HIP_MEMORY_SCOPE_AGENT) < target) {
        __builtin_amdgcn_s_sleep(1);
      }
    }
    __syncthreads();

    // ---- stage h_{t-1} from LLC into LDS (bank-swizzled float4) ----
    {
      const ull* src64 = (const ull*)(hb + ((t + 1) & 1) * DIMS);
#pragma unroll
      for (int c = 0; c < 2; ++c) {
        int L = tid + c * 256;  // float4 index 0..511
        ull a  = __hip_atomic_load(src64 + 2 * L,     __ATOMIC_RELAXED, __HIP_MEMORY_SCOPE_AGENT);
        ull bq = __hip_atomic_load(src64 + 2 * L + 1, __ATOMIC_RELAXED, __HIP_MEMORY_SCOPE_AGENT);
        int kko = L >> 5, j2o = L & 31;
        float4 v;
        v.x = __uint_as_float((unsigned)a);
        v.y = __uint_as_float((unsigned)(a >> 32));
        v.z = __uint_as_float((unsigned)bq);
        v.w = __uint_as_float((unsigned)(bq >> 32));
        hs4[kko * 32 + (j2o ^ (kko & 7))] = v;
      }
    }
    __syncthreads();

    // ---- matvec: row `grow`, K-chunk kk ----
    float acc = 0.f;
#pragma unroll
    for (int j4 = 0; j4 < 16; ++j4) {
      uint4 w = w16[j4][r][kk];
      float4 ha = hs4[kk * 32 + ((2 * j4)     ^ (kk & 7))];
      float4 hc = hs4[kk * 32 + ((2 * j4 + 1) ^ (kk & 7))];
      acc += bflo(w.x) * ha.x + bfhi(w.x) * ha.y + bflo(w.y) * ha.z + bfhi(w.y) * ha.w;
      acc += bflo(w.z) * hc.x + bfhi(w.z) * hc.y + bflo(w.w) * hc.z + bfhi(w.w) * hc.w;
    }
#pragma unroll
    for (int off = 8; off > 0; off >>= 1) acc += __shfl_xor(acc, off, 16);

    if (kk == 0) {
      float y = acc + zpre;
      float hcur = tanhf(y);
      // publish FIRST (critical path for all other blocks)
      __hip_atomic_store(&hb[(t & 1) * DIMS + grow], hcur,
                         __ATOMIC_RELAXED, __HIP_MEMORY_SCOPE_AGENT);
      // then residual output + next-step prefetch (off critical path)
      ZO[(size_t)t * DIMS + grow] = xpre + hcur;
      if (t + 1 < SEQ) {
        zpre = ZO[(size_t)(t + 1) * DIMS + grow];
        xpre = X[(size_t)(t + 1) * DIMS + grow];
      }
    }
    __syncthreads();   // vmcnt(0) in every wave: h stores at LLC before the add
    if (tid == 0)
      __hip_atomic_fetch_add(&ctr[((t + 1) & 7) * 16], 1,
                             __ATOMIC_RELAXED, __HIP_MEMORY_SCOPE_AGENT);
  }
}

// ---------- launch ----------
extern "C" void kernel_launch(void* const* d_in, const int* in_sizes, int n_in,
                              void* d_out, int out_size, void* d_ws, size_t ws_size,
                              hipStream_t stream) {
  (void)in_sizes; (void)n_in; (void)out_size; (void)ws_size;
  const float* X    = (const float*)d_in[0];
  const float* Whi  = (const float*)d_in[1];
  const float* Whh  = (const float*)d_in[2];
  const float* bias = (const float*)d_in[3];
  const float* h0   = (const float*)d_in[4];
  float* out = (float*)d_out;

  float* hb = (float*)d_ws;                                   // 2*DIMS floats = 16 KB
  int*  ctr = (int*)((char*)d_ws + 2 * DIMS * sizeof(float)); // 8 counters x 64B = 512 B

  hipMemsetAsync(ctr, 0, 8 * 16 * sizeof(int), stream);

  dim3 g(SEQ / 64, DIMS / 64);
  gemm_z<<<g, 256, 0, stream>>>(X, Whi, bias, out);
  rnn_seq<<<NBLK, 256, 0, stream>>>(X, Whh, h0, out, hb, ctr);
}

// Round 5
// 10445.435 us; speedup vs baseline: 1.6545x; 1.6545x over previous
//
#include <hip/hip_runtime.h>
#include <hip/hip_bf16.h>
#include <stdint.h>

#define DIMS 2048
#define SEQ  4096
#define NBLK 256   // persistent blocks (one per CU)
#define RPB  8     // rows of W_hh per block (NBLK*RPB == DIMS)

typedef unsigned long long ull;
typedef float v4f __attribute__((ext_vector_type(4)));

// ---------- helpers ----------
__device__ __forceinline__ unsigned pk_bf16(float a, float b) {
  // round-to-nearest-even bf16, packed (a -> low16, b -> high16)
  unsigned ua = __float_as_uint(a);
  ua += 0x7fffu + ((ua >> 16) & 1u);
  unsigned ub = __float_as_uint(b);
  ub += 0x7fffu + ((ub >> 16) & 1u);
  return (ua >> 16) | (ub & 0xffff0000u);
}
__device__ __forceinline__ float bflo(unsigned u) { return __uint_as_float(u << 16); }
__device__ __forceinline__ float bfhi(unsigned u) { return __uint_as_float(u & 0xffff0000u); }

// ---------- Kernel A: Z = X @ W_hi^T + b  (fp32, written into d_out) ----------
__global__ __launch_bounds__(256) void gemm_z(const float* __restrict__ X,
                                              const float* __restrict__ W,
                                              const float* __restrict__ bias,
                                              float* __restrict__ Z) {
  __shared__ float xs[64][33];
  __shared__ float ws[64][33];
  const int tid = threadIdx.x;
  const int tx = tid & 15;
  const int ty = tid >> 4;
  const int s0 = blockIdx.x * 64;
  const int d0 = blockIdx.y * 64;

  float acc[4][4] = {};

  for (int k0 = 0; k0 < DIMS; k0 += 32) {
#pragma unroll
    for (int i = 0; i < 2; ++i) {
      int idx = tid + i * 256;
      int r = idx >> 3;
      int c = (idx & 7) << 2;
      float4 xv = *(const float4*)&X[(size_t)(s0 + r) * DIMS + k0 + c];
      xs[r][c] = xv.x; xs[r][c + 1] = xv.y; xs[r][c + 2] = xv.z; xs[r][c + 3] = xv.w;
      float4 wv = *(const float4*)&W[(size_t)(d0 + r) * DIMS + k0 + c];
      ws[r][c] = wv.x; ws[r][c + 1] = wv.y; ws[r][c + 2] = wv.z; ws[r][c + 3] = wv.w;
    }
    __syncthreads();
#pragma unroll
    for (int k = 0; k < 32; ++k) {
      float a_[4], b_[4];
#pragma unroll
      for (int i = 0; i < 4; ++i) a_[i] = xs[ty * 4 + i][k];
#pragma unroll
      for (int j = 0; j < 4; ++j) b_[j] = ws[tx * 4 + j][k];
#pragma unroll
      for (int i = 0; i < 4; ++i)
#pragma unroll
        for (int j = 0; j < 4; ++j) acc[i][j] += a_[i] * b_[j];
    }
    __syncthreads();
  }

  const float4 bv = *(const float4*)&bias[d0 + tx * 4];
#pragma unroll
  for (int i = 0; i < 4; ++i) {
    float4 o;
    o.x = acc[i][0] + bv.x; o.y = acc[i][1] + bv.y;
    o.z = acc[i][2] + bv.z; o.w = acc[i][3] + bv.w;
    *(float4*)&Z[(size_t)(s0 + ty * 4 + i) * DIMS + d0 + tx * 4] = o;
  }
}

// ---------- Kernel B: persistent recurrence ----------
// 256 blocks x 256 threads; block b owns rows [8b, 8b+8). W_hh lives in VGPRs
// (thread (r,c) holds row 8b+r, K-slice [64c, 64c+64) as 8 uint4 of bf16 pairs).
// Protocol (per step): thread t polls producer t's flag, then fetches exactly
// block t's 8 h values (32 B, one asm dwordx4 pair, sc0 sc1 -> LLC-coherent),
// packs to bf16, stages into 4 KB LDS. One barrier, matvec from regs+LDS,
// 32-lane shfl reduce, publish 4x8B per block, barrier (vmcnt drain), flag,
// THEN the off-path ZO store + next-step Z/X prefetch (so the L3 round trip
// for Z/X is NOT inside the publish->flag critical chain, unlike R2/R3).
__global__ __launch_bounds__(256) void rnn_seq(const float* __restrict__ X,
                                               const float* __restrict__ Whh,
                                               const float* __restrict__ h0,
                                               float* __restrict__ ZO,   // d_out: Z in, out overwrites
                                               float* __restrict__ hb,   // ws: 2*DIMS floats
                                               int* __restrict__ flags)  // ws: NBLK flags, stride 16 ints
{
  __shared__ uint4 hsb[DIMS / 8];   // 256 x 16B: h_{t-1} as packed bf16, XOR-swizzled

  const int tid = threadIdx.x;
  const int b   = blockIdx.x;
  const int r   = tid >> 5;        // 0..7   local row
  const int c   = tid & 31;        // 0..31  K-chunk (64 elems)
  const int brow = b * RPB;
  const int grow = brow + r;

  // ---- one-time: this thread's W_hh slice -> 8 uint4 of bf16 pairs (32 VGPRs) ----
  uint4 wq[8];
  {
    const float* wrow = Whh + (size_t)grow * DIMS + c * 64;
#pragma unroll
    for (int m = 0; m < 8; ++m) {
      float4 a = *(const float4*)(wrow + m * 8);
      float4 d = *(const float4*)(wrow + m * 8 + 4);
      wq[m] = make_uint4(pk_bf16(a.x, a.y), pk_bf16(a.z, a.w),
                         pk_bf16(d.x, d.y), pk_bf16(d.z, d.w));
    }
  }

  // ---- publish h0 slice into slot 1 ----
  if (tid < RPB)
    __hip_atomic_store(&hb[DIMS + brow + tid], h0[brow + tid],
                       __ATOMIC_RELAXED, __HIP_MEMORY_SCOPE_AGENT);
  // first-step Z/X prefetch (c==0 lanes own a row each)
  float zpre = 0.f, xpre = 0.f;
  if (c == 0) { zpre = ZO[grow]; xpre = X[grow]; }
  __syncthreads();   // drains h0 stores
  if (tid == 0)
    __hip_atomic_store(&flags[b * 16], 1, __ATOMIC_RELAXED, __HIP_MEMORY_SCOPE_AGENT);

  for (int t = 0; t < SEQ; ++t) {
    // ---- thread t: wait for producer block `tid`, then fetch ITS 8 h values ----
    while (__hip_atomic_load(&flags[tid * 16], __ATOMIC_RELAXED,
                             __HIP_MEMORY_SCOPE_AGENT) < t + 1) { }
    const float* src = hb + (size_t)((t + 1) & 1) * DIMS + tid * 8;
    v4f fa, fb;
    asm volatile(
        "global_load_dwordx4 %0, %2, off sc0 sc1\n\t"
        "global_load_dwordx4 %1, %3, off sc0 sc1\n\t"
        "s_waitcnt vmcnt(0)"
        : "=&v"(fa), "=&v"(fb)
        : "v"(src), "v"(src + 4)
        : "memory");
    {
      const int c0 = tid >> 3, m0 = tid & 7;
      hsb[c0 * 8 + (m0 ^ (c0 & 7))] =
          make_uint4(pk_bf16(fa.x, fa.y), pk_bf16(fa.z, fa.w),
                     pk_bf16(fb.x, fb.y), pk_bf16(fb.z, fb.w));
    }
    __syncthreads();   // all 2048 h values staged

    // ---- matvec: row `grow`, K-slice [64c, 64c+64), all operands regs/LDS ----
    float acc = 0.f;
#pragma unroll
    for (int m = 0; m < 8; ++m) {
      uint4 w = wq[m];
      uint4 h = hsb[c * 8 + (m ^ (c & 7))];
      acc += bflo(w.x) * bflo(h.x) + bfhi(w.x) * bfhi(h.x);
      acc += bflo(w.y) * bflo(h.y) + bfhi(w.y) * bfhi(h.y);
      acc += bflo(w.z) * bflo(h.z) + bfhi(w.z) * bfhi(h.z);
      acc += bflo(w.w) * bflo(h.w) + bfhi(w.w) * bfhi(h.w);
    }
#pragma unroll
    for (int off = 16; off > 0; off >>= 1) acc += __shfl_xor(acc, off);

    float hcur = 0.f;
    if (c == 0) hcur = tanhf(acc + zpre);
    // pack the wave's two row results (lanes 0 and 32) into one 8B store
    float hhi = __shfl(hcur, 32);
    if ((tid & 63) == 0) {
      ull pk = ((ull)__float_as_uint(hhi) << 32) | (ull)__float_as_uint(hcur);
      __hip_atomic_store((ull*)(hb + (size_t)(t & 1) * DIMS + brow) + (tid >> 6),
                         pk, __ATOMIC_RELAXED, __HIP_MEMORY_SCOPE_AGENT);
    }
    __syncthreads();   // each wave drains its vmcnt -> publish at LLC
    if (tid == 0)
      __hip_atomic_store(&flags[b * 16], t + 2, __ATOMIC_RELAXED, __HIP_MEMORY_SCOPE_AGENT);

    // off-critical-path: residual out + next-step Z/X prefetch (AFTER flag)
    if (c == 0) {
      ZO[(size_t)t * DIMS + grow] = xpre + hcur;
      if (t + 1 < SEQ) {
        zpre = ZO[(size_t)(t + 1) * DIMS + grow];
        xpre = X[(size_t)(t + 1) * DIMS + grow];
      }
    }
  }
}

// ---------- launch ----------
extern "C" void kernel_launch(void* const* d_in, const int* in_sizes, int n_in,
                              void* d_out, int out_size, void* d_ws, size_t ws_size,
                              hipStream_t stream) {
  (void)in_sizes; (void)n_in; (void)out_size; (void)ws_size;
  const float* X    = (const float*)d_in[0];
  const float* Whi  = (const float*)d_in[1];
  const float* Whh  = (const float*)d_in[2];
  const float* bias = (const float*)d_in[3];
  const float* h0   = (const float*)d_in[4];
  float* out = (float*)d_out;

  float* hb   = (float*)d_ws;                                   // 2*DIMS floats = 16 KB
  int*  flags = (int*)((char*)d_ws + 2 * DIMS * sizeof(float)); // 256 flags x 64B = 16 KB

  hipMemsetAsync(flags, 0, NBLK * 16 * sizeof(int), stream);

  dim3 g(SEQ / 64, DIMS / 64);
  gemm_z<<<g, 256, 0, stream>>>(X, Whi, bias, out);
  rnn_seq<<<NBLK, 256, 0, stream>>>(X, Whh, h0, out, hb, flags);
}

// Round 6
// 8072.763 us; speedup vs baseline: 2.1408x; 1.2939x over previous
//
#include <hip/hip_runtime.h>
#include <hip/hip_bf16.h>
#include <stdint.h>

#define DIMS 2048
#define SEQ  4096
#define NBLK 256   // persistent blocks (one per CU)
#define RPB  8     // rows of W_hh per block
#define NW   1024  // tagged words per slot (= DIMS/2)

typedef unsigned long long ull;
typedef unsigned int v4u __attribute__((ext_vector_type(4)));

// ---------- helpers ----------
__device__ __forceinline__ unsigned pk_bf16(float a, float b) {
  // round-to-nearest-even bf16, packed (a -> low16, b -> high16)
  unsigned ua = __float_as_uint(a);
  ua += 0x7fffu + ((ua >> 16) & 1u);
  unsigned ub = __float_as_uint(b);
  ub += 0x7fffu + ((ub >> 16) & 1u);
  return (ua >> 16) | (ub & 0xffff0000u);
}
__device__ __forceinline__ float bflo(unsigned u) { return __uint_as_float(u << 16); }
__device__ __forceinline__ float bfhi(unsigned u) { return __uint_as_float(u & 0xffff0000u); }

// ---------- Kernel A: Z = X @ W_hi^T + b  (fp32, written into d_out) ----------
__global__ __launch_bounds__(256) void gemm_z(const float* __restrict__ X,
                                              const float* __restrict__ W,
                                              const float* __restrict__ bias,
                                              float* __restrict__ Z) {
  __shared__ float xs[64][33];
  __shared__ float ws[64][33];
  const int tid = threadIdx.x;
  const int tx = tid & 15;
  const int ty = tid >> 4;
  const int s0 = blockIdx.x * 64;
  const int d0 = blockIdx.y * 64;

  float acc[4][4] = {};

  for (int k0 = 0; k0 < DIMS; k0 += 32) {
#pragma unroll
    for (int i = 0; i < 2; ++i) {
      int idx = tid + i * 256;
      int r = idx >> 3;
      int c = (idx & 7) << 2;
      float4 xv = *(const float4*)&X[(size_t)(s0 + r) * DIMS + k0 + c];
      xs[r][c] = xv.x; xs[r][c + 1] = xv.y; xs[r][c + 2] = xv.z; xs[r][c + 3] = xv.w;
      float4 wv = *(const float4*)&W[(size_t)(d0 + r) * DIMS + k0 + c];
      ws[r][c] = wv.x; ws[r][c + 1] = wv.y; ws[r][c + 2] = wv.z; ws[r][c + 3] = wv.w;
    }
    __syncthreads();
#pragma unroll
    for (int k = 0; k < 32; ++k) {
      float a_[4], b_[4];
#pragma unroll
      for (int i = 0; i < 4; ++i) a_[i] = xs[ty * 4 + i][k];
#pragma unroll
      for (int j = 0; j < 4; ++j) b_[j] = ws[tx * 4 + j][k];
#pragma unroll
      for (int i = 0; i < 4; ++i)
#pragma unroll
        for (int j = 0; j < 4; ++j) acc[i][j] += a_[i] * b_[j];
    }
    __syncthreads();
  }

  const float4 bv = *(const float4*)&bias[d0 + tx * 4];
#pragma unroll
  for (int i = 0; i < 4; ++i) {
    float4 o;
    o.x = acc[i][0] + bv.x; o.y = acc[i][1] + bv.y;
    o.z = acc[i][2] + bv.z; o.w = acc[i][3] + bv.w;
    *(float4*)&Z[(size_t)(s0 + ty * 4 + i) * DIMS + d0 + tx * 4] = o;
  }
}

// ---------- Kernel B: persistent recurrence, tagged-word protocol ----------
// hb2: 2 slots x 1024 words of 8B = (bf16 h[2g] | bf16 h[2g+1] | tag<<32).
// Producer: wave w of block b publishes word g = b*4+w with tag t+1 into slot
// t&1 — ONE relaxed agent store, no flag, no drain, no post-publish barrier.
// Consumer thread t speculatively loads its 4 words (32B, dwordx4 pair sc0 sc1)
// each poll iteration; when all 4 tags == t, data is already in registers.
// LDS h-tile double-buffered -> single __syncthreads per step.
// Slot safety: publish(t+2) (overwrites step-t words) happens after this block
// observed all tag-(t+1) words; each block publishes t+1 only after all its
// threads' step-t reads completed (reads drain pre-barrier) -> safe.
__global__ __launch_bounds__(256) void rnn_seq(const float* __restrict__ X,
                                               const float* __restrict__ Whh,
                                               const float* __restrict__ h0,
                                               float* __restrict__ ZO,   // d_out: Z in, out overwrites
                                               ull* __restrict__ hb2)    // ws: 2*NW tagged words
{
  __shared__ uint4 hsb[2][DIMS / 8];   // double-buffered packed-bf16 h, swizzled

  const int tid = threadIdx.x;
  const int b   = blockIdx.x;
  const int r   = tid >> 5;        // 0..7   local row
  const int c   = tid & 31;        // 0..31  K-chunk (64 elems)
  const int grow = b * RPB + r;

  // ---- one-time: this thread's W_hh slice -> 8 uint4 of bf16 pairs ----
  uint4 wq[8];
  {
    const float* wrow = Whh + (size_t)grow * DIMS + c * 64;
#pragma unroll
    for (int m = 0; m < 8; ++m) {
      float4 a = *(const float4*)(wrow + m * 8);
      float4 d = *(const float4*)(wrow + m * 8 + 4);
      wq[m] = make_uint4(pk_bf16(a.x, a.y), pk_bf16(a.z, a.w),
                         pk_bf16(d.x, d.y), pk_bf16(d.z, d.w));
    }
  }

  // ---- publish h0 as tagged words (tag 0) into slot 1 ----
  if (tid < 4) {
    unsigned pair = pk_bf16(h0[b * RPB + 2 * tid], h0[b * RPB + 2 * tid + 1]);
    __hip_atomic_store(&hb2[NW + b * 4 + tid], (ull)pair,
                       __ATOMIC_RELAXED, __HIP_MEMORY_SCOPE_AGENT);
  }
  // first-step Z/X prefetch (c==0 lanes: lanes 0 and 32 of each wave)
  float zpre = 0.f, xpre = 0.f;
  if (c == 0) { zpre = ZO[grow]; xpre = X[grow]; }

  for (int t = 0; t < SEQ; ++t) {
    // ---- poll own 4 tagged words; data arrives WITH detection ----
    const ull* src = hb2 + (size_t)((t + 1) & 1) * NW + tid * 4;
    const unsigned want = (unsigned)t;
    v4u p01, p23;
    do {
      asm volatile(
          "global_load_dwordx4 %0, %2, off sc0 sc1\n\t"
          "global_load_dwordx4 %1, %3, off sc0 sc1\n\t"
          "s_waitcnt vmcnt(0)"
          : "=&v"(p01), "=&v"(p23)
          : "v"(src), "v"(src + 2)
          : "memory");
    } while (p01.y != want || p01.w != want || p23.y != want || p23.w != want);

    // ---- stage packed data dwords into LDS (swizzled, double-buffered) ----
    {
      const int c0 = tid >> 3, m0 = tid & 7;
      hsb[t & 1][c0 * 8 + (m0 ^ (c0 & 7))] = make_uint4(p01.x, p01.z, p23.x, p23.z);
    }
    __syncthreads();   // the ONLY barrier per step

    // ---- matvec: row `grow`, K-slice [64c, 64c+64), bf16 x bf16 ----
    float acc = 0.f;
#pragma unroll
    for (int m = 0; m < 8; ++m) {
      uint4 w = wq[m];
      uint4 h = hsb[t & 1][c * 8 + (m ^ (c & 7))];
      acc += bflo(w.x) * bflo(h.x) + bfhi(w.x) * bfhi(h.x);
      acc += bflo(w.y) * bflo(h.y) + bfhi(w.y) * bfhi(h.y);
      acc += bflo(w.z) * bflo(h.z) + bfhi(w.z) * bfhi(h.z);
      acc += bflo(w.w) * bflo(h.w) + bfhi(w.w) * bfhi(h.w);
    }
#pragma unroll
    for (int off = 16; off > 0; off >>= 1) acc += __shfl_xor(acc, off);

    float hcur = 0.f;
    if (c == 0) hcur = tanhf(acc + zpre);     // lanes 0 and 32 of each wave
    float hhi = __shfl(hcur, 32);             // lane0 gets lane32's row
    if ((tid & 63) == 0) {
      // publish this wave's 2 rows: one tagged 8B store, nothing else in front
      ull pk = ((ull)(unsigned)(t + 1) << 32) | (ull)pk_bf16(hcur, hhi);
      __hip_atomic_store(&hb2[(size_t)(t & 1) * NW + b * 4 + (tid >> 6)], pk,
                         __ATOMIC_RELAXED, __HIP_MEMORY_SCOPE_AGENT);
    }

    // off-critical-path: residual out + next-step Z/X prefetch
    if (c == 0) {
      ZO[(size_t)t * DIMS + grow] = xpre + hcur;
      if (t + 1 < SEQ) {
        zpre = ZO[(size_t)(t + 1) * DIMS + grow];
        xpre = X[(size_t)(t + 1) * DIMS + grow];
      }
    }
  }
}

// ---------- launch ----------
extern "C" void kernel_launch(void* const* d_in, const int* in_sizes, int n_in,
                              void* d_out, int out_size, void* d_ws, size_t ws_size,
                              hipStream_t stream) {
  (void)in_sizes; (void)n_in; (void)out_size; (void)ws_size;
  const float* X    = (const float*)d_in[0];
  const float* Whi  = (const float*)d_in[1];
  const float* Whh  = (const float*)d_in[2];
  const float* bias = (const float*)d_in[3];
  const float* h0   = (const float*)d_in[4];
  float* out = (float*)d_out;

  ull* hb2 = (ull*)d_ws;   // 2*NW tagged words = 16 KB

  // tag bytes 0xFF never match any step tag -> replay-safe
  hipMemsetAsync(hb2, 0xFF, 2 * NW * sizeof(ull), stream);

  dim3 g(SEQ / 64, DIMS / 64);
  gemm_z<<<g, 256, 0, stream>>>(X, Whi, bias, out);
  rnn_seq<<<NBLK, 256, 0, stream>>>(X, Whh, h0, out, hb2);
}